// Round 1
// baseline (49.595 us; speedup 1.0000x reference)
//
#include <hip/hip_runtime.h>

typedef __bf16 bf16x8 __attribute__((ext_vector_type(8)));
typedef float f32x4 __attribute__((ext_vector_type(4)));

#define HEADS 16   // B*nH
#define TT 64      // T
#define FDIM 8192  // H*W*C
#define CHUNKF 256
#define NCHUNK 32  // FDIM / CHUNKF

// ---------------- Kernel 1: partial S = Q K^T over one f-chunk (bf16 MFMA) --------------
// grid (NCHUNK, HEADS), block 256 (4 waves). Wave w computes rows [16w,16w+16) x all 64 q.
// A-frag (16x32): lane l holds A[l&15][(l>>4)*8 + i]  -> Q row, 8 contiguous f
// B-frag (32x16): lane l holds B[(l>>4)*8+i][l&15] = K[l&15][k...] -> same addressing on K
// D: row=(l>>4)*4+i, col=l&15   [verified layout, learn_hip m89/m91]
__global__ __launch_bounds__(256) void qk_partial(const float* __restrict__ Q,
                                                  const float* __restrict__ Km,
                                                  float* __restrict__ part) {
    const int chunk = blockIdx.x;
    const int h     = blockIdx.y;
    const int lane  = threadIdx.x & 63;
    const int w     = threadIdx.x >> 6;
    const int r16   = lane & 15;
    const int kb    = (chunk << 8) + ((lane >> 4) << 3);  // f-offset for this lane

    const float* qp  = Q  + ((size_t)h * TT + (w << 4) + r16) * FDIM + kb;
    const float* kp0 = Km + ((size_t)h * TT + r16) * FDIM + kb;

    f32x4 acc[4] = {{0.f,0.f,0.f,0.f},{0.f,0.f,0.f,0.f},{0.f,0.f,0.f,0.f},{0.f,0.f,0.f,0.f}};

    #pragma unroll
    for (int ks = 0; ks < 8; ++ks) {            // 8 k-steps of 32 -> 256 f per block
        bf16x8 a;
        #pragma unroll
        for (int i = 0; i < 8; ++i) a[i] = (__bf16)qp[ks * 32 + i];
        #pragma unroll
        for (int nb = 0; nb < 4; ++nb) {        // 4 column tiles of 16 q
            const float* kp = kp0 + (size_t)(nb << 4) * FDIM + ks * 32;
            bf16x8 b;
            #pragma unroll
            for (int i = 0; i < 8; ++i) b[i] = (__bf16)kp[i];
            acc[nb] = __builtin_amdgcn_mfma_f32_16x16x32_bf16(a, b, acc[nb], 0, 0, 0);
        }
    }

    // write fp32 partial tile: part[chunk][h][p][q]
    float* pp = part + ((size_t)chunk * HEADS + h) * (TT * TT);
    #pragma unroll
    for (int nb = 0; nb < 4; ++nb) {
        const int q = (nb << 4) + r16;
        #pragma unroll
        for (int i = 0; i < 4; ++i) {
            const int p = (w << 4) + ((lane >> 4) << 2) + i;
            pp[p * TT + q] = acc[nb][i];
        }
    }
}

// ---------------- Kernel 2: reduce partials over chunks, scale, store transposed ----------
// St[h][q][p] = (1/1024) * sum_c part[c][h][p][q]
__global__ __launch_bounds__(256) void reduce_s(const float* __restrict__ part,
                                                float* __restrict__ St) {
    const int e = blockIdx.x * 256 + threadIdx.x;   // 16*4096 = 65536 elements
    const int h = e >> 12;
    const int r = e & 4095;                         // r = p*64 + q
    float s = 0.f;
    #pragma unroll
    for (int c = 0; c < NCHUNK; ++c)
        s += part[((size_t)c * HEADS + h) * (TT * TT) + r];
    const int p = r >> 6, q = r & 63;
    St[h * (TT * TT) + q * TT + p] = s * (1.0f / 1024.0f);
}

// ---------------- Kernel 3: O[h][p][j] = gauss[j>>3] * sum_q St[h][q][p] * V[h][q][j] -----
// grid (64, HEADS), block 256 = 4 waves. Wave: 64 columns (lane=col), 32 p's.
// S reads are wave-uniform -> scalar loads; inner loop is v_fmac_f32 with SGPR operand.
__global__ __launch_bounds__(256) void sv_out(const float* __restrict__ V,
                                              const float* __restrict__ St,
                                              float* __restrict__ out) {
    const int h    = blockIdx.y;
    const int tid  = threadIdx.x;
    const int lane = tid & 63;
    const int w    = tid >> 6;
    const int col  = blockIdx.x * 128 + ((w >> 1) << 6) + lane;  // 2 col-groups per block
    const int pbase = (w & 1) << 5;                              // 2 p-halves per block
    const int sbase = __builtin_amdgcn_readfirstlane(h * (TT * TT) + pbase);

    const float* Vh = V + (size_t)h * TT * FDIM + col;

    float acc[32];
    #pragma unroll
    for (int p = 0; p < 32; ++p) acc[p] = 0.f;

    for (int q0 = 0; q0 < TT; q0 += 8) {
        float v[8];
        #pragma unroll
        for (int i = 0; i < 8; ++i) v[i] = Vh[(size_t)(q0 + i) * FDIM];
        #pragma unroll
        for (int i = 0; i < 8; ++i) {
            const float* Sq = St + sbase + (q0 + i) * TT;
            #pragma unroll
            for (int p = 0; p < 32; ++p) acc[p] = fmaf(Sq[p], v[i], acc[p]);
        }
    }

    // Gaussian weight for this column's (h,w) position; separable normalizer (exact).
    const int m   = col >> 3;
    const float dx = (float)(m >> 5) - 15.5f;
    const float dy = (float)(m & 31) - 15.5f;
    float sx = 0.f;
    #pragma unroll
    for (int x = 0; x < 32; ++x) {
        const float d = (float)x - 15.5f;
        sx += expf(-d * d * (1.0f / 50.0f));
    }
    const float g = expf(-(dx * dx + dy * dy) * (1.0f / 50.0f)) / (sx * sx);

    float* O = out + (size_t)h * TT * FDIM + col;
    #pragma unroll
    for (int p = 0; p < 32; ++p) O[(size_t)(pbase + p) * FDIM] = acc[p] * g;
}

extern "C" void kernel_launch(void* const* d_in, const int* in_sizes, int n_in,
                              void* d_out, int out_size, void* d_ws, size_t ws_size,
                              hipStream_t stream) {
    const float* Q  = (const float*)d_in[0];
    const float* Km = (const float*)d_in[1];
    const float* V  = (const float*)d_in[2];
    float* out  = (float*)d_out;
    float* part = (float*)d_out;   // 8 MB partials live inside the 33.5 MB output buffer
    float* St   = (float*)d_ws;    // 256 KB reduced/transposed S

    qk_partial<<<dim3(NCHUNK, HEADS), 256, 0, stream>>>(Q, Km, part);
    reduce_s<<<dim3((HEADS * TT * TT) / 256), 256, 0, stream>>>(part, St);
    sv_out<<<dim3(FDIM / 128, HEADS), 256, 0, stream>>>(V, St, out);
}

// Round 2
// 45.446 us; speedup vs baseline: 1.0913x; 1.0913x over previous
//
#include <hip/hip_runtime.h>
#include <cmath>

typedef __bf16 bf16x8 __attribute__((ext_vector_type(8)));
typedef float f32x4 __attribute__((ext_vector_type(4)));
typedef float f32x2 __attribute__((ext_vector_type(2)));

#define HEADS 16   // B*nH
#define TT 64      // T
#define FDIM 8192  // H*W*C
#define NCHUNK 32  // K-split chunks
#define CHUNKF 256 // FDIM / NCHUNK

// ---------------- Kernel 1: partial S = Q K^T over one f-chunk (bf16 MFMA) --------------
// grid (NCHUNK, HEADS), block 256 (4 waves, 2x2 wave tiling: each wave 32p x 32q).
// A-frag (16x32): lane l holds A[l&15][(l>>4)*8 + i]; B-frag same addressing on K rows.
// D: row=(l>>4)*4+i, col=l&15   [verified layout, learn_hip m89/m91; R0 passed]
__global__ __launch_bounds__(256) void qk_partial(const float* __restrict__ Q,
                                                  const float* __restrict__ Km,
                                                  float* __restrict__ part) {
    const int chunk = blockIdx.x;
    const int h     = blockIdx.y;
    const int lane  = threadIdx.x & 63;
    const int w     = threadIdx.x >> 6;
    const int pr    = (w & 1) << 5;   // wave's p-origin (0 or 32)
    const int qr    = (w >> 1) << 5;  // wave's q-origin (0 or 32)
    const int r16   = lane & 15;
    const int g     = lane >> 4;
    const int kb    = (chunk << 8) + (g << 3);  // float offset of this lane's 8-f group

    const float4* qp = (const float4*)(Q  + ((size_t)h * TT + pr + r16) * FDIM + kb);
    const float4* kp = (const float4*)(Km + ((size_t)h * TT + qr + r16) * FDIM + kb);
    // row stride: FDIM/4 = 2048 float4; +16 rows = 32768 float4

    f32x4 acc[2][2] = {{{0.f,0.f,0.f,0.f},{0.f,0.f,0.f,0.f}},
                       {{0.f,0.f,0.f,0.f},{0.f,0.f,0.f,0.f}}};

    #pragma unroll
    for (int ks = 0; ks < 8; ++ks) {            // 8 k-steps of 32 f
        bf16x8 a[2], b[2];
        #pragma unroll
        for (int t = 0; t < 2; ++t) {
            const float4 x0 = qp[(size_t)t * 32768 + ks * 8];
            const float4 x1 = qp[(size_t)t * 32768 + ks * 8 + 1];
            a[t][0]=(__bf16)x0.x; a[t][1]=(__bf16)x0.y; a[t][2]=(__bf16)x0.z; a[t][3]=(__bf16)x0.w;
            a[t][4]=(__bf16)x1.x; a[t][5]=(__bf16)x1.y; a[t][6]=(__bf16)x1.z; a[t][7]=(__bf16)x1.w;
            const float4 y0 = kp[(size_t)t * 32768 + ks * 8];
            const float4 y1 = kp[(size_t)t * 32768 + ks * 8 + 1];
            b[t][0]=(__bf16)y0.x; b[t][1]=(__bf16)y0.y; b[t][2]=(__bf16)y0.z; b[t][3]=(__bf16)y0.w;
            b[t][4]=(__bf16)y1.x; b[t][5]=(__bf16)y1.y; b[t][6]=(__bf16)y1.z; b[t][7]=(__bf16)y1.w;
        }
        #pragma unroll
        for (int i = 0; i < 2; ++i)
            #pragma unroll
            for (int j = 0; j < 2; ++j)
                acc[i][j] = __builtin_amdgcn_mfma_f32_16x16x32_bf16(a[i], b[j], acc[i][j], 0, 0, 0);
    }

    // write fp32 partial tile: part[chunk][h][p][q]  (p-major -> 64B store segments)
    float* pp = part + ((size_t)chunk * HEADS + h) * (TT * TT);
    #pragma unroll
    for (int i = 0; i < 2; ++i)
        #pragma unroll
        for (int j = 0; j < 2; ++j)
            #pragma unroll
            for (int r = 0; r < 4; ++r)
                pp[(pr + (i << 4) + (g << 2) + r) * TT + (qr + (j << 4) + r16)] = acc[i][j][r];
}

// ---------------- Kernel 2: reduce partials over chunks, scale, store transposed ----------
// St[h][q][p] = (1/1024) * sum_c part[c][h][p][q]
__global__ __launch_bounds__(256) void reduce_s(const float* __restrict__ part,
                                                float* __restrict__ St) {
    const int e = blockIdx.x * 256 + threadIdx.x;   // 16*4096 = 65536 elements
    const int h = e >> 12;
    const int r = e & 4095;                         // r = p*64 + q
    float s = 0.f;
    #pragma unroll
    for (int c = 0; c < NCHUNK; ++c)
        s += part[((size_t)c * HEADS + h) * (TT * TT) + r];
    const int p = r >> 6, q = r & 63;
    St[h * (TT * TT) + q * TT + p] = s * (1.0f / 1024.0f);
}

// ---------------- Kernel 3: O[h][p][j] = gauss[j>>3] * sum_q St[h][q][p] * V[h][q][j] -----
// grid (64, HEADS), block 256 = 4 waves. Lane=column; S reads wave-uniform (s_load path);
// inner loop float2 -> v_pk_fma_f32 (2 FMA/instr). Gaussian normalizer from host.
__global__ __launch_bounds__(256) void sv_out(const float* __restrict__ V,
                                              const float* __restrict__ St,
                                              float* __restrict__ out,
                                              const float g_norm) {
    const int h    = blockIdx.y;
    const int tid  = threadIdx.x;
    const int lane = tid & 63;
    const int w    = tid >> 6;
    const int col  = blockIdx.x * 128 + ((w >> 1) << 6) + lane;
    const int pbase = (w & 1) << 5;
    const int sbase = __builtin_amdgcn_readfirstlane(h * (TT * TT) + pbase);

    const float* Vh = V + (size_t)h * TT * FDIM + col;

    f32x2 acc[16];
    #pragma unroll
    for (int p2 = 0; p2 < 16; ++p2) acc[p2] = (f32x2){0.f, 0.f};

    for (int q0 = 0; q0 < TT; q0 += 8) {
        float v[8];
        #pragma unroll
        for (int i = 0; i < 8; ++i) v[i] = Vh[(size_t)(q0 + i) * FDIM];
        #pragma unroll
        for (int i = 0; i < 8; ++i) {
            const f32x2* S2 = (const f32x2*)(St + sbase + (q0 + i) * TT);
            const f32x2 vv = {v[i], v[i]};
            #pragma unroll
            for (int p2 = 0; p2 < 16; ++p2)
                acc[p2] += S2[p2] * vv;   // -ffp-contract -> v_pk_fma_f32
        }
    }

    // Gaussian weight for this column's (h,w) position (normalizer precomputed on host).
    const int m   = col >> 3;
    const float dx = (float)(m >> 5) - 15.5f;
    const float dy = (float)(m & 31) - 15.5f;
    const float gg = expf(-(dx * dx + dy * dy) * 0.02f) * g_norm;

    float* O = out + (size_t)h * TT * FDIM + col;
    #pragma unroll
    for (int p2 = 0; p2 < 16; ++p2) {
        O[(size_t)(pbase + 2 * p2)     * FDIM] = acc[p2].x * gg;
        O[(size_t)(pbase + 2 * p2 + 1) * FDIM] = acc[p2].y * gg;
    }
}

extern "C" void kernel_launch(void* const* d_in, const int* in_sizes, int n_in,
                              void* d_out, int out_size, void* d_ws, size_t ws_size,
                              hipStream_t stream) {
    const float* Q  = (const float*)d_in[0];
    const float* Km = (const float*)d_in[1];
    const float* V  = (const float*)d_in[2];
    float* out  = (float*)d_out;
    float* part = (float*)d_out;   // 8 MB partials live inside the 33.5 MB output buffer
    float* St   = (float*)d_ws;    // 256 KB reduced/transposed S

    // Host-side separable Gaussian normalizer (exact, deterministic):
    double sx = 0.0;
    for (int x = 0; x < 32; ++x) { const double d = (double)x - 15.5; sx += exp(-d * d / 50.0); }
    const float g_norm = (float)(1.0 / (sx * sx));

    qk_partial<<<dim3(NCHUNK, HEADS), 256, 0, stream>>>(Q, Km, part);
    reduce_s<<<dim3((HEADS * TT * TT) / 256), 256, 0, stream>>>(part, St);
    sv_out<<<dim3(FDIM / 128, HEADS), 256, 0, stream>>>(V, St, out, g_norm);
}